// Round 3
// baseline (5358.334 us; speedup 1.0000x reference)
//
#include <hip/hip_runtime.h>
#include <hip/hip_bf16.h>

// B=2048, T=100, I=1, H=512. Output: h at t=84..99 -> (2048,16,512) fp32.
// ws layout (bytes):
//   Wc  bf16 [2560][512] @ 0        (rows 0..511 = W2_w, 512..2559 = W_hh)
//   hbf bf16 [2048][512] @ 2621440
//   cst f32  [2048][512] @ 4718592
//   sbuf f32 [2048][512] @ 8912896
//   gpre f32 [2048][2048]@ 13107200   (end 29884416)

typedef __attribute__((ext_vector_type(8))) short s16x8;
typedef __attribute__((ext_vector_type(4))) float f32x4;

#define LOG2E 1.4426950408889634f

__device__ __forceinline__ float fexp2(float x) {
  float r; asm("v_exp_f32 %0, %1\n\ts_nop 1" : "=v"(r) : "v"(x)); return r;
}
__device__ __forceinline__ float frcp(float x) {
  float r; asm("v_rcp_f32 %0, %1\n\ts_nop 1" : "=v"(r) : "v"(x)); return r;
}
__device__ __forceinline__ float ftanh(float y) {   // tanh(y) = 1 - 2/(1+e^{2y})
  return 1.0f - 2.0f * frcp(1.0f + fexp2(y * (2.0f * LOG2E)));
}
__device__ __forceinline__ float fsig(float y) {
  return frcp(1.0f + fexp2(-y * LOG2E));
}

__device__ __forceinline__ void gl_lds16(const void* g, void* l) {
  __builtin_amdgcn_global_load_lds(
      (const __attribute__((address_space(1))) void*)g,
      (__attribute__((address_space(3))) void*)l, 16, 0, 0);
}

// ---------------- prologue: zero h,c ; convert weights to bf16 -------------
__global__ __launch_bounds__(256) void darnn_prologue(
    const float* __restrict__ W2w, const float* __restrict__ Whh,
    __hip_bfloat16* __restrict__ Wc, __hip_bfloat16* __restrict__ hbf,
    float* __restrict__ cst)
{
  const int gtid = blockIdx.x * 256 + threadIdx.x;        // 0..131071
  s16x8 z8 = {0, 0, 0, 0, 0, 0, 0, 0};
  ((s16x8*)hbf)[gtid] = z8;                               // 2048*512 bf16
  f32x4 zf = {0.f, 0.f, 0.f, 0.f};
  ((f32x4*)cst)[gtid] = zf;                               // 2048*512 f32
  ((f32x4*)cst)[gtid + 131072] = zf;
  for (int i = gtid; i < 2560 * 512; i += 131072) {
    int n = i >> 9, k = i & 511;
    float v = (n < 512) ? W2w[(n << 9) + k] : Whh[((n - 512) << 9) + k];
    Wc[i] = __float2bfloat16(v);
  }
}

// ------------- per-step GEMM: [s | gates_pre] = h @ Wc^T -------------------
// 512 WGs x 256 thr. Tile 64x160, BK=64. C/D layout: col=lane&15,
// row=(lane>>4)*4+e (m89-verified). A/B frag: row/col=lane&15, k=(lane>>4)*8.
__global__ __launch_bounds__(256) void darnn_gemm(
    const __hip_bfloat16* __restrict__ hbf, const __hip_bfloat16* __restrict__ Wc,
    float* __restrict__ sbuf, float* __restrict__ gpre)
{
  const int wg = blockIdx.x, tid = threadIdx.x;
  const int lane = tid & 63, wv = tid >> 6;

  __shared__ __align__(16) short ldsA[64 * 64];    // h tile   [64 rows][64 k]
  __shared__ __align__(16) short ldsB[160 * 64];   // Wc tile  [160 rows][64 k]

  const int mt = wg >> 4, nt = wg & 15;            // 32 x 16 tiles
  const int m0 = mt << 6, n0 = nt * 160;
  const int wm = wv >> 1, wn = wv & 1;             // wave = 32x80 sub-tile
  const int lr = lane & 15, lq = lane >> 4;
  const int r8 = lane >> 3, kk8 = (lane & 7) << 3;

  f32x4 acc[2][5];
#pragma unroll
  for (int i = 0; i < 2; ++i)
#pragma unroll
    for (int j = 0; j < 5; ++j) acc[i][j] = {0.f, 0.f, 0.f, 0.f};

  for (int k0 = 0; k0 < 512; k0 += 64) {
    // stage 28 x 1KB chunks (8 A + 20 B), 7 per wave, each lane covers 16B
#pragma unroll
    for (int cc = 0; cc < 7; ++cc) {
      int c = wv * 7 + cc;
      if (c < 8) {
        gl_lds16(hbf + ((size_t)(m0 + (c << 3) + r8) << 9) + (k0 + kk8),
                 (void*)(ldsA + (c << 9)));
      } else {
        int cb = c - 8;
        gl_lds16(Wc + ((size_t)(n0 + (cb << 3) + r8) << 9) + (k0 + kk8),
                 (void*)(ldsB + (cb << 9)));
      }
    }
    __syncthreads();
#pragma unroll
    for (int kh = 0; kh < 2; ++kh) {
      s16x8 af[2], bfr[5];
      int kk = (kh << 5) + (lq << 3);
#pragma unroll
      for (int i = 0; i < 2; ++i)
        af[i] = *(const s16x8*)(ldsA + ((wm << 5) + (i << 4) + lr) * 64 + kk);
#pragma unroll
      for (int j = 0; j < 5; ++j)
        bfr[j] = *(const s16x8*)(ldsB + (wn * 80 + (j << 4) + lr) * 64 + kk);
#pragma unroll
      for (int i = 0; i < 2; ++i)
#pragma unroll
        for (int j = 0; j < 5; ++j)
          acc[i][j] = __builtin_amdgcn_mfma_f32_16x16x32_bf16(
              af[i], bfr[j], acc[i][j], 0, 0, 0);
    }
    __syncthreads();
  }
#pragma unroll
  for (int i = 0; i < 2; ++i)
#pragma unroll
    for (int j = 0; j < 5; ++j) {
      int row0 = m0 + (wm << 5) + (i << 4) + (lq << 2);
      int col = n0 + wn * 80 + (j << 4) + lr;
#pragma unroll
      for (int e = 0; e < 4; ++e) {
        float v = acc[i][j][e];
        if (col < 512) sbuf[((size_t)(row0 + e) << 9) + col] = v;
        else gpre[((size_t)(row0 + e) << 11) + (col - 512)] = v;
      }
    }
}

// ------------- per-step attention + LSTM (one batch-row per wave) ----------
// 512 WGs x 256 thr; WG handles rows 4wg..4wg+3.
__global__ __launch_bounds__(256) void darnn_attn_lstm(
    const float* __restrict__ x, const float* __restrict__ W1w,
    const float* __restrict__ W1b, const float* __restrict__ W2b,
    const float* __restrict__ vw, const float* __restrict__ Wih,
    const float* __restrict__ bih, const float* __restrict__ bhh,
    const float* __restrict__ sbuf, const float* __restrict__ gpre,
    float* __restrict__ cst, __hip_bfloat16* __restrict__ hbf,
    float* __restrict__ out, int t)
{
  const int wg = blockIdx.x, tid = threadIdx.x;
  const int lane = tid & 63, wv = tid >> 6;

  __shared__ float l_logit[4][104];
  __shared__ float l_wm[4];

  // attention constants: per-lane slice of 8 h-indices
  float cw1[8], cbb[8], vvv[8];
  {
    int h0 = lane * 8;
#pragma unroll
    for (int e = 0; e < 8; ++e) {
      cw1[e] = W1w[h0 + e];
      cbb[e] = W1b[h0 + e] + W2b[h0 + e];
      vvv[e] = vw[h0 + e];
    }
  }

  const int b = (wg << 2) + wv;
  const float* xb = x + b * 100;
  float base[8];
  {
    const f32x4 s0 = *(const f32x4*)(sbuf + ((size_t)b << 9) + lane * 8);
    const f32x4 s1 = *(const f32x4*)(sbuf + ((size_t)b << 9) + lane * 8 + 4);
#pragma unroll
    for (int e = 0; e < 4; ++e) {
      base[e] = s0[e] + cbb[e];
      base[4 + e] = s1[e] + cbb[4 + e];
    }
  }
  // logits over suffix t..99 (wave-cooperative over h)
  for (int tp = t; tp < 100; ++tp) {
    float xv = xb[tp];
    float a = 0.f;
#pragma unroll
    for (int e = 0; e < 8; ++e) {
      float arg = fmaf(xv, cw1[e], base[e]);
      a = fmaf(vvv[e], ftanh(arg), a);
    }
    a += __shfl_xor(a, 32); a += __shfl_xor(a, 16); a += __shfl_xor(a, 8);
    a += __shfl_xor(a, 4);  a += __shfl_xor(a, 2);  a += __shfl_xor(a, 1);
    if (lane == 0) l_logit[wv][tp] = a;
  }
  __syncthreads();
  // softmax over [t,100) + weighted mean of x (wave-local)
  {
    int t0 = t + lane, t1 = t + 64 + lane;
    float v0 = (t0 < 100) ? l_logit[wv][t0] : -1e30f;
    float v1 = (t1 < 100) ? l_logit[wv][t1] : -1e30f;
    float mx = fmaxf(v0, v1);
    mx = fmaxf(mx, __shfl_xor(mx, 32)); mx = fmaxf(mx, __shfl_xor(mx, 16));
    mx = fmaxf(mx, __shfl_xor(mx, 8));  mx = fmaxf(mx, __shfl_xor(mx, 4));
    mx = fmaxf(mx, __shfl_xor(mx, 2));  mx = fmaxf(mx, __shfl_xor(mx, 1));
    float e0 = (t0 < 100) ? fexp2((v0 - mx) * LOG2E) : 0.f;
    float e1 = (t1 < 100) ? fexp2((v1 - mx) * LOG2E) : 0.f;
    float x0 = (t0 < 100) ? xb[t0] : 0.f;
    float x1 = (t1 < 100) ? xb[t1] : 0.f;
    float se = e0 + e1, sx = e0 * x0 + e1 * x1;
    se += __shfl_xor(se, 32); sx += __shfl_xor(sx, 32);
    se += __shfl_xor(se, 16); sx += __shfl_xor(sx, 16);
    se += __shfl_xor(se, 8);  sx += __shfl_xor(sx, 8);
    se += __shfl_xor(se, 4);  sx += __shfl_xor(sx, 4);
    se += __shfl_xor(se, 2);  sx += __shfl_xor(sx, 2);
    se += __shfl_xor(se, 1);  sx += __shfl_xor(sx, 1);
    if (lane == 0) l_wm[wv] = sx * frcp(se * (float)(100 - t));
  }
  __syncthreads();
  // LSTM update: 4 rows x 512 cols over 256 threads (j = tid or tid+256)
  float wihc[2][4], bias[2][4];
#pragma unroll
  for (int p = 0; p < 2; ++p) {
    int j = tid + (p << 8);
#pragma unroll
    for (int g = 0; g < 4; ++g) {
      wihc[p][g] = Wih[(g << 9) + j];
      bias[p][g] = bih[(g << 9) + j] + bhh[(g << 9) + j];
    }
  }
#pragma unroll
  for (int p = 0; p < 8; ++p) {
    int widx = tid + (p << 8);
    int row = widx >> 9;                       // 0..3
    int j = widx & 511;                        // = tid or tid+256
    int b2 = (wg << 2) + row;
    int sel = p & 1;
    float wmv = l_wm[row];
    const float* gp = gpre + ((size_t)b2 << 11);
    float gi = gp[j]        + fmaf(wmv, wihc[sel][0], bias[sel][0]);
    float gf = gp[512 + j]  + fmaf(wmv, wihc[sel][1], bias[sel][1]);
    float gg = gp[1024 + j] + fmaf(wmv, wihc[sel][2], bias[sel][2]);
    float go = gp[1536 + j] + fmaf(wmv, wihc[sel][3], bias[sel][3]);
    size_t cidx = ((size_t)b2 << 9) + j;
    float cn = fsig(gf) * cst[cidx] + fsig(gi) * ftanh(gg);
    float hn = fsig(go) * ftanh(cn);
    cst[cidx] = cn;
    hbf[cidx] = __float2bfloat16(hn);
    if (t >= 84) out[((size_t)b2 << 13) + ((size_t)(t - 84) << 9) + j] = hn;
  }
}

extern "C" void kernel_launch(void* const* d_in, const int* in_sizes, int n_in,
                              void* d_out, int out_size, void* d_ws, size_t ws_size,
                              hipStream_t stream) {
  const float* x   = (const float*)d_in[0];
  const float* W1w = (const float*)d_in[1];
  const float* W1b = (const float*)d_in[2];
  const float* W2w = (const float*)d_in[3];
  const float* W2b = (const float*)d_in[4];
  const float* vw  = (const float*)d_in[5];
  // d_in[6] = v_b : cancels in softmax, unused
  const float* Wih = (const float*)d_in[7];
  const float* bih = (const float*)d_in[8];
  const float* Whh = (const float*)d_in[9];
  const float* bhh = (const float*)d_in[10];
  float* out = (float*)d_out;

  char* ws = (char*)d_ws;
  __hip_bfloat16* Wc  = (__hip_bfloat16*)(ws);
  __hip_bfloat16* hbf = (__hip_bfloat16*)(ws + 2621440);
  float* cst  = (float*)(ws + 4718592);
  float* sbuf = (float*)(ws + 8912896);
  float* gpre = (float*)(ws + 13107200);

  darnn_prologue<<<dim3(512), dim3(256), 0, stream>>>(W2w, Whh, Wc, hbf, cst);
  for (int t = 0; t < 100; ++t) {
    darnn_gemm<<<dim3(512), dim3(256), 0, stream>>>(hbf, Wc, sbuf, gpre);
    darnn_attn_lstm<<<dim3(512), dim3(256), 0, stream>>>(
        x, W1w, W1b, W2b, vw, Wih, bih, bhh, sbuf, gpre, cst, hbf, out, t);
  }
}

// Round 7
// 4491.798 us; speedup vs baseline: 1.1929x; 1.1929x over previous
//
#include <hip/hip_runtime.h>
#include <hip/hip_bf16.h>

// B=2048, T=100, I=1, H=512. Output: h at t=84..99 -> (2048,16,512) fp32.
// Step structure: K1 s-GEMM (h@W2^T -> sbuf) ; K2 attn (-> wmbuf) ;
//                 K3 gates-GEMM (h@Whh_interleaved^T) + fused LSTM epilogue.
// ws layout (bytes):
//   Wcs  bf16 [512][512]   @ 0         (= W2_w)
//   Wcg  bf16 [2048][512]  @ 524288    (row 4j+g = Whh[g*512+j])
//   hbf  bf16 [2048][512]  @ 2621440
//   cst  f32  [2048][512]  @ 4718592
//   sbuf f32  [2048][512]  @ 8912896
//   wmbuf f32 [2048]       @ 13107200
//   wihg  f32 [2048]       @ 13115392  (row 4j+g = W_ih[g*512+j])
//   biasg f32 [2048]       @ 13123584  (b_ih+b_hh, interleaved)

typedef __attribute__((ext_vector_type(8))) short s16x8;
typedef __attribute__((ext_vector_type(4))) float f32x4;

#define LOG2E 1.4426950408889634f

__device__ __forceinline__ float fexp2(float x) {
  float r; asm("v_exp_f32 %0, %1\n\ts_nop 1" : "=v"(r) : "v"(x)); return r;
}
__device__ __forceinline__ float frcp(float x) {
  float r; asm("v_rcp_f32 %0, %1\n\ts_nop 1" : "=v"(r) : "v"(x)); return r;
}
__device__ __forceinline__ float ftanh(float y) {   // tanh(y) = 1 - 2/(1+e^{2y})
  return 1.0f - 2.0f * frcp(1.0f + fexp2(y * (2.0f * LOG2E)));
}
__device__ __forceinline__ float fsig(float y) {
  return frcp(1.0f + fexp2(-y * LOG2E));
}

__device__ __forceinline__ void gl_lds16(const void* g, void* l) {
  __builtin_amdgcn_global_load_lds(
      (const __attribute__((address_space(1))) void*)g,
      (__attribute__((address_space(3))) void*)l, 16, 0, 0);
}

// ---------------- prologue: zero h,c ; build bf16/interleaved weights ------
__global__ __launch_bounds__(256) void darnn_prologue(
    const float* __restrict__ W2w, const float* __restrict__ Whh,
    const float* __restrict__ Wih, const float* __restrict__ bih,
    const float* __restrict__ bhh,
    __hip_bfloat16* __restrict__ Wcs, __hip_bfloat16* __restrict__ Wcg,
    __hip_bfloat16* __restrict__ hbf, float* __restrict__ cst,
    float* __restrict__ wihg, float* __restrict__ biasg)
{
  const int gtid = blockIdx.x * 256 + threadIdx.x;        // 0..131071
  s16x8 z8 = {0, 0, 0, 0, 0, 0, 0, 0};
  ((s16x8*)hbf)[gtid] = z8;                               // 2048*512 bf16
  f32x4 zf = {0.f, 0.f, 0.f, 0.f};
  ((f32x4*)cst)[gtid] = zf;                               // 2048*512 f32
  ((f32x4*)cst)[gtid + 131072] = zf;
  // Wcs = bf16(W2w), same layout (512*512 = 2 per thread)
  Wcs[2 * gtid]     = __float2bfloat16(W2w[2 * gtid]);
  Wcs[2 * gtid + 1] = __float2bfloat16(W2w[2 * gtid + 1]);
  // Wcg: row r=4j+g <- Whh row g*512+j   (2048*512 = 8 per thread, same row)
  {
    int base = gtid * 8;
    int r = base >> 9, kk = base & 511;
    int j = r >> 2, g = r & 3;
    const float* src = Whh + ((size_t)((g << 9) + j) << 9) + kk;
#pragma unroll
    for (int e = 0; e < 8; ++e) Wcg[base + e] = __float2bfloat16(src[e]);
  }
  if (gtid < 2048) {
    int j = gtid >> 2, g = gtid & 3;
    int src = (g << 9) + j;
    wihg[gtid]  = Wih[src];
    biasg[gtid] = bih[src] + bhh[src];
  }
}

// ---------------- K1: sbuf = h @ W2^T  (M=2048,N=512,K=512) ----------------
// 256 WGs x 256 thr, tile 64x64, BK=64. Frag layouts m89-verified.
__global__ __launch_bounds__(256, 2) void darnn_sgemm(
    const __hip_bfloat16* __restrict__ hbf, const __hip_bfloat16* __restrict__ Wcs,
    float* __restrict__ sbuf)
{
  const int wg = blockIdx.x, tid = threadIdx.x;
  const int lane = tid & 63, wv = tid >> 6;

  __shared__ __align__(16) short ldsA[64 * 64];
  __shared__ __align__(16) short ldsB[64 * 64];

  const int mt = wg >> 3, nt = wg & 7;
  const int m0 = mt << 6, n0 = nt << 6;
  const int wm = wv >> 1, wn = wv & 1;             // wave = 32x32 quadrant
  const int lr = lane & 15, lq = lane >> 4;
  const int r8 = lane >> 3, kk8 = (lane & 7) << 3;

  f32x4 acc[2][2];
#pragma unroll
  for (int i = 0; i < 2; ++i)
#pragma unroll
    for (int j = 0; j < 2; ++j) acc[i][j] = {0.f, 0.f, 0.f, 0.f};

  for (int k0 = 0; k0 < 512; k0 += 64) {
#pragma unroll
    for (int cc = 0; cc < 4; ++cc) {
      int c = wv * 4 + cc;
      if (c < 8) {
        gl_lds16(hbf + ((size_t)(m0 + (c << 3) + r8) << 9) + (k0 + kk8),
                 (void*)(ldsA + (c << 9)));
      } else {
        int cb = c - 8;
        gl_lds16(Wcs + ((size_t)(n0 + (cb << 3) + r8) << 9) + (k0 + kk8),
                 (void*)(ldsB + (cb << 9)));
      }
    }
    __syncthreads();
#pragma unroll
    for (int kh = 0; kh < 2; ++kh) {
      s16x8 af[2], bfr[2];
      int kk = (kh << 5) + (lq << 3);
#pragma unroll
      for (int i = 0; i < 2; ++i)
        af[i] = *(const s16x8*)(ldsA + ((wm << 5) + (i << 4) + lr) * 64 + kk);
#pragma unroll
      for (int j = 0; j < 2; ++j)
        bfr[j] = *(const s16x8*)(ldsB + ((wn << 5) + (j << 4) + lr) * 64 + kk);
#pragma unroll
      for (int i = 0; i < 2; ++i)
#pragma unroll
        for (int j = 0; j < 2; ++j)
          acc[i][j] = __builtin_amdgcn_mfma_f32_16x16x32_bf16(
              af[i], bfr[j], acc[i][j], 0, 0, 0);
    }
    __syncthreads();
  }
#pragma unroll
  for (int i = 0; i < 2; ++i)
#pragma unroll
    for (int j = 0; j < 2; ++j) {
      int row0 = m0 + (wm << 5) + (i << 4) + (lq << 2);
      int col = n0 + (wn << 5) + (j << 4) + lr;
#pragma unroll
      for (int e = 0; e < 4; ++e)
        sbuf[((size_t)(row0 + e) << 9) + col] = acc[i][j][e];
    }
}

// ---------------- K2: attention -> wmbuf  (one row per WG) -----------------
// 2048 WGs x 256 thr; wave w handles tp = t+w, t+w+4, ... (strided).
__global__ __launch_bounds__(256, 8) void darnn_attn(
    const float* __restrict__ x, const float* __restrict__ W1w,
    const float* __restrict__ W1b, const float* __restrict__ W2b,
    const float* __restrict__ vw, const float* __restrict__ sbuf,
    float* __restrict__ wmbuf, int t)
{
  const int b = blockIdx.x, tid = threadIdx.x;
  const int lane = tid & 63, wv = tid >> 6;

  __shared__ float l_logit[100];
  __shared__ float xs[104];

  if (tid < 100) xs[tid] = x[b * 100 + tid];

  // per-lane slice of 8 h-indices
  float cw1[8], base[8], vvv[8];
  {
    int h0 = lane * 8;
    const f32x4 s0 = *(const f32x4*)(sbuf + ((size_t)b << 9) + h0);
    const f32x4 s1 = *(const f32x4*)(sbuf + ((size_t)b << 9) + h0 + 4);
#pragma unroll
    for (int e = 0; e < 8; ++e) {
      cw1[e] = W1w[h0 + e];
      vvv[e] = vw[h0 + e];
      float s = (e < 4) ? s0[e] : s1[e - 4];
      base[e] = s + W1b[h0 + e] + W2b[h0 + e];
    }
  }
  __syncthreads();

  for (int tp = t + wv; tp < 100; tp += 4) {
    float xv = xs[tp];
    float a = 0.f;
#pragma unroll
    for (int e = 0; e < 8; ++e) {
      float arg = fmaf(xv, cw1[e], base[e]);
      a = fmaf(vvv[e], ftanh(arg), a);
    }
    a += __shfl_xor(a, 32); a += __shfl_xor(a, 16); a += __shfl_xor(a, 8);
    a += __shfl_xor(a, 4);  a += __shfl_xor(a, 2);  a += __shfl_xor(a, 1);
    if (lane == 0) l_logit[tp] = a;
  }
  __syncthreads();

  if (wv == 0) {
    int t0 = t + lane, t1 = t + 64 + lane;
    float v0 = (t0 < 100) ? l_logit[t0] : -1e30f;
    float v1 = (t1 < 100) ? l_logit[t1] : -1e30f;
    float mx = fmaxf(v0, v1);
    mx = fmaxf(mx, __shfl_xor(mx, 32)); mx = fmaxf(mx, __shfl_xor(mx, 16));
    mx = fmaxf(mx, __shfl_xor(mx, 8));  mx = fmaxf(mx, __shfl_xor(mx, 4));
    mx = fmaxf(mx, __shfl_xor(mx, 2));  mx = fmaxf(mx, __shfl_xor(mx, 1));
    float e0 = (t0 < 100) ? fexp2((v0 - mx) * LOG2E) : 0.f;
    float e1 = (t1 < 100) ? fexp2((v1 - mx) * LOG2E) : 0.f;
    float x0 = (t0 < 100) ? xs[t0] : 0.f;
    float x1 = (t1 < 100) ? xs[t1] : 0.f;
    float se = e0 + e1, sx = e0 * x0 + e1 * x1;
    se += __shfl_xor(se, 32); sx += __shfl_xor(sx, 32);
    se += __shfl_xor(se, 16); sx += __shfl_xor(sx, 16);
    se += __shfl_xor(se, 8);  sx += __shfl_xor(sx, 8);
    se += __shfl_xor(se, 4);  sx += __shfl_xor(sx, 4);
    se += __shfl_xor(se, 2);  sx += __shfl_xor(sx, 2);
    se += __shfl_xor(se, 1);  sx += __shfl_xor(sx, 1);
    if (lane == 0) wmbuf[b] = sx * frcp(se * (float)(100 - t));
  }
}

// ------- K3: gates = h @ Wcg^T (+wm*wihg+biasg) ; fused LSTM epilogue ------
// 512 WGs x 256 thr, tile 64x128 (gate-space cols), BK=64.
__global__ __launch_bounds__(256, 2) void darnn_ggemm_lstm(
    const __hip_bfloat16* __restrict__ hbfin, const __hip_bfloat16* __restrict__ Wcg,
    const float* __restrict__ wmbuf, const float* __restrict__ wihg,
    const float* __restrict__ biasg, float* __restrict__ cst,
    __hip_bfloat16* __restrict__ hbf, float* __restrict__ out, int t)
{
  const int wg = blockIdx.x, tid = threadIdx.x;
  const int lane = tid & 63, wv = tid >> 6;

  __shared__ __align__(16) short ldsA[64 * 64];      // 8 KB
  __shared__ __align__(16) short ldsB[128 * 64];     // 16 KB
  __shared__ __align__(16) float ldsG[64 * 128];     // 32 KB

  const int mt = wg >> 4, nt = wg & 15;
  const int m0 = mt << 6, n0 = nt << 7;              // n0 in gate space (2048)
  const int wm = wv >> 1, wn = wv & 1;               // wave = 32x64 sub-tile
  const int lr = lane & 15, lq = lane >> 4;
  const int r8 = lane >> 3, kk8 = (lane & 7) << 3;

  f32x4 acc[2][4];
#pragma unroll
  for (int i = 0; i < 2; ++i)
#pragma unroll
    for (int j = 0; j < 4; ++j) acc[i][j] = {0.f, 0.f, 0.f, 0.f};

  for (int k0 = 0; k0 < 512; k0 += 64) {
#pragma unroll
    for (int cc = 0; cc < 6; ++cc) {
      int c = wv * 6 + cc;
      if (c < 8) {
        gl_lds16(hbfin + ((size_t)(m0 + (c << 3) + r8) << 9) + (k0 + kk8),
                 (void*)(ldsA + (c << 9)));
      } else {
        int cb = c - 8;
        gl_lds16(Wcg + ((size_t)(n0 + (cb << 3) + r8) << 9) + (k0 + kk8),
                 (void*)(ldsB + (cb << 9)));
      }
    }
    __syncthreads();
#pragma unroll
    for (int kh = 0; kh < 2; ++kh) {
      s16x8 af[2], bfr[4];
      int kk = (kh << 5) + (lq << 3);
#pragma unroll
      for (int i = 0; i < 2; ++i)
        af[i] = *(const s16x8*)(ldsA + ((wm << 5) + (i << 4) + lr) * 64 + kk);
#pragma unroll
      for (int j = 0; j < 4; ++j)
        bfr[j] = *(const s16x8*)(ldsB + ((wn << 6) + (j << 4) + lr) * 64 + kk);
#pragma unroll
      for (int i = 0; i < 2; ++i)
#pragma unroll
        for (int j = 0; j < 4; ++j)
          acc[i][j] = __builtin_amdgcn_mfma_f32_16x16x32_bf16(
              af[i], bfr[j], acc[i][j], 0, 0, 0);
    }
    __syncthreads();
  }
  // stage gate pre-activations to LDS (local [row][col], col=4j+g)
#pragma unroll
  for (int i = 0; i < 2; ++i)
#pragma unroll
    for (int j = 0; j < 4; ++j) {
      int row0 = (wm << 5) + (i << 4) + (lq << 2);
      int col = (wn << 6) + (j << 4) + lr;
#pragma unroll
      for (int e = 0; e < 4; ++e)
        ldsG[(row0 + e) * 128 + col] = acc[i][j][e];
    }
  __syncthreads();

  // LSTM update: 64 rows x 32 hidden-j per WG; thread -> (row, jl)
  {
    const int jl = tid & 31;                          // local hidden 0..31
    const int rb = tid >> 5;                          // row base 0..7
    const int jg = (n0 >> 2) + jl;                    // global hidden
    const f32x4 wih4 = *(const f32x4*)(wihg + n0 + (jl << 2));
    const f32x4 bia4 = *(const f32x4*)(biasg + n0 + (jl << 2));
#pragma unroll
    for (int p = 0; p < 8; ++p) {
      int r = (p << 3) + rb;                          // local row 0..63
      int b = m0 + r;
      f32x4 g4 = *(const f32x4*)(ldsG + r * 128 + (jl << 2));
      float wmv = wmbuf[b];
      float gi = fmaf(wmv, wih4[0], bia4[0]) + g4[0];
      float gf = fmaf(wmv, wih4[1], bia4[1]) + g4[1];
      float gg = fmaf(wmv, wih4[2], bia4[2]) + g4[2];
      float go = fmaf(wmv, wih4[3], bia4[3]) + g4[3];
      size_t cidx = ((size_t)b << 9) + jg;
      float cn = fsig(gf) * cst[cidx] + fsig(gi) * ftanh(gg);
      float hn = fsig(go) * ftanh(cn);
      cst[cidx] = cn;
      hbf[cidx] = __float2bfloat16(hn);
      if (t >= 84) out[((size_t)b << 13) + ((size_t)(t - 84) << 9) + jg] = hn;
    }
  }
}

extern "C" void kernel_launch(void* const* d_in, const int* in_sizes, int n_in,
                              void* d_out, int out_size, void* d_ws, size_t ws_size,
                              hipStream_t stream) {
  const float* x   = (const float*)d_in[0];
  const float* W1w = (const float*)d_in[1];
  const float* W1b = (const float*)d_in[2];
  const float* W2w = (const float*)d_in[3];
  const float* W2b = (const float*)d_in[4];
  const float* vw  = (const float*)d_in[5];
  // d_in[6] = v_b : cancels in softmax, unused
  const float* Wih = (const float*)d_in[7];
  const float* bih = (const float*)d_in[8];
  const float* Whh = (const float*)d_in[9];
  const float* bhh = (const float*)d_in[10];
  float* out = (float*)d_out;

  char* ws = (char*)d_ws;
  __hip_bfloat16* Wcs = (__hip_bfloat16*)(ws);
  __hip_bfloat16* Wcg = (__hip_bfloat16*)(ws + 524288);
  __hip_bfloat16* hbf = (__hip_bfloat16*)(ws + 2621440);
  float* cst   = (float*)(ws + 4718592);
  float* sbuf  = (float*)(ws + 8912896);
  float* wmbuf = (float*)(ws + 13107200);
  float* wihg  = (float*)(ws + 13115392);
  float* biasg = (float*)(ws + 13123584);

  darnn_prologue<<<dim3(512), dim3(256), 0, stream>>>(
      W2w, Whh, Wih, bih, bhh, Wcs, Wcg, hbf, cst, wihg, biasg);
  for (int t = 0; t < 100; ++t) {
    darnn_sgemm<<<dim3(256), dim3(256), 0, stream>>>(hbf, Wcs, sbuf);
    darnn_attn<<<dim3(2048), dim3(256), 0, stream>>>(
        x, W1w, W1b, W2b, vw, sbuf, wmbuf, t);
    darnn_ggemm_lstm<<<dim3(512), dim3(256), 0, stream>>>(
        hbf, Wcg, wmbuf, wihg, biasg, cst, hbf, out, t);
  }
}

// Round 8
// 4147.638 us; speedup vs baseline: 1.2919x; 1.0830x over previous
//
#include <hip/hip_runtime.h>
#include <hip/hip_bf16.h>

// B=2048, T=100, I=1, H=512. Output: h at t=84..99 -> (2048,16,512) fp32.
// Step: K_A darnn_gemms (768 WGs: gates-GEMM -> gpre | s-GEMM -> sbuf) ;
//       K_B darnn_attn_lstm (2048 WGs, 1 row/WG: attn -> wm, LSTM update).
// ws layout (bytes), total 29884416 (== round-1-proven usage):
//   Wcs  bf16 [512][512]   @ 0         (= W2_w)
//   Wcg  bf16 [2048][512]  @ 524288    (row 4j+g = Whh[g*512+j])
//   hbf  bf16 [2048][512]  @ 2621440
//   cst  f32  [2048][512]  @ 4718592
//   sbuf f32  [2048][512]  @ 8912896
//   gpre f32  [2048][2048] @ 13107200  (col 4j+g, interleaved gates)

typedef __attribute__((ext_vector_type(8))) short s16x8;
typedef __attribute__((ext_vector_type(4))) float f32x4;

#define LOG2E 1.4426950408889634f

__device__ __forceinline__ float fexp2(float x) {
  float r; asm("v_exp_f32 %0, %1\n\ts_nop 1" : "=v"(r) : "v"(x)); return r;
}
__device__ __forceinline__ float frcp(float x) {
  float r; asm("v_rcp_f32 %0, %1\n\ts_nop 1" : "=v"(r) : "v"(x)); return r;
}
__device__ __forceinline__ float ftanh(float y) {   // tanh(y) = 1 - 2/(1+e^{2y})
  return 1.0f - 2.0f * frcp(1.0f + fexp2(y * (2.0f * LOG2E)));
}
__device__ __forceinline__ float fsig(float y) {
  return frcp(1.0f + fexp2(-y * LOG2E));
}

__device__ __forceinline__ void gl_lds16(const void* g, void* l) {
  __builtin_amdgcn_global_load_lds(
      (const __attribute__((address_space(1))) void*)g,
      (__attribute__((address_space(3))) void*)l, 16, 0, 0);
}

// ---------------- prologue: zero h,c ; build bf16 weights ------------------
__global__ __launch_bounds__(256) void darnn_prologue(
    const float* __restrict__ W2w, const float* __restrict__ Whh,
    __hip_bfloat16* __restrict__ Wcs, __hip_bfloat16* __restrict__ Wcg,
    __hip_bfloat16* __restrict__ hbf, float* __restrict__ cst)
{
  const int gtid = blockIdx.x * 256 + threadIdx.x;        // 0..131071
  s16x8 z8 = {0, 0, 0, 0, 0, 0, 0, 0};
  ((s16x8*)hbf)[gtid] = z8;                               // 2048*512 bf16
  f32x4 zf = {0.f, 0.f, 0.f, 0.f};
  ((f32x4*)cst)[gtid] = zf;                               // 2048*512 f32
  ((f32x4*)cst)[gtid + 131072] = zf;
  // Wcs = bf16(W2w), same layout (512*512 = 2 per thread)
  Wcs[2 * gtid]     = __float2bfloat16(W2w[2 * gtid]);
  Wcs[2 * gtid + 1] = __float2bfloat16(W2w[2 * gtid + 1]);
  // Wcg: row r=4j+g <- Whh row g*512+j   (2048*512 = 8 per thread, same row)
  {
    int base = gtid * 8;
    int r = base >> 9, kk = base & 511;
    int j = r >> 2, g = r & 3;
    const float* src = Whh + ((size_t)((g << 9) + j) << 9) + kk;
#pragma unroll
    for (int e = 0; e < 8; ++e) Wcg[base + e] = __float2bfloat16(src[e]);
  }
}

// -------- K_A: merged GEMMs.  WG 0..511: gates = h @ Wcg^T -> gpre ---------
//                              WG 512..767: s = h @ Wcs^T -> sbuf
// Frag layouts m89-verified: C/D col=lane&15, row=(lane>>4)*4+e;
// A/B frag row/col=lane&15, k=(lane>>4)*8.
__global__ __launch_bounds__(256, 2) void darnn_gemms(
    const __hip_bfloat16* __restrict__ hbf, const __hip_bfloat16* __restrict__ Wcs,
    const __hip_bfloat16* __restrict__ Wcg,
    float* __restrict__ sbuf, float* __restrict__ gpre)
{
  const int wg = blockIdx.x, tid = threadIdx.x;
  const int lane = tid & 63, wv = tid >> 6;

  __shared__ __align__(16) short ldsA[64 * 64];      // 8 KB
  __shared__ __align__(16) short ldsB[128 * 64];     // 16 KB (sgemm uses half)

  const int lr = lane & 15, lq = lane >> 4;
  const int r8 = lane >> 3, kk8 = (lane & 7) << 3;
  const int wm = wv >> 1, wn = wv & 1;

  if (wg < 512) {
    // ---- gates GEMM: tile 64x128 (gate cols), BK=64 ----
    const int mt = wg >> 4, nt = wg & 15;
    const int m0 = mt << 6, n0 = nt << 7;
    f32x4 acc[2][4];
#pragma unroll
    for (int i = 0; i < 2; ++i)
#pragma unroll
      for (int j = 0; j < 4; ++j) acc[i][j] = {0.f, 0.f, 0.f, 0.f};

    for (int k0 = 0; k0 < 512; k0 += 64) {
#pragma unroll
      for (int cc = 0; cc < 6; ++cc) {
        int c = wv * 6 + cc;
        if (c < 8) {
          gl_lds16(hbf + ((size_t)(m0 + (c << 3) + r8) << 9) + (k0 + kk8),
                   (void*)(ldsA + (c << 9)));
        } else {
          int cb = c - 8;
          gl_lds16(Wcg + ((size_t)(n0 + (cb << 3) + r8) << 9) + (k0 + kk8),
                   (void*)(ldsB + (cb << 9)));
        }
      }
      __syncthreads();
#pragma unroll
      for (int kh = 0; kh < 2; ++kh) {
        s16x8 af[2], bfr[4];
        int kk = (kh << 5) + (lq << 3);
#pragma unroll
        for (int i = 0; i < 2; ++i)
          af[i] = *(const s16x8*)(ldsA + ((wm << 5) + (i << 4) + lr) * 64 + kk);
#pragma unroll
        for (int j = 0; j < 4; ++j)
          bfr[j] = *(const s16x8*)(ldsB + ((wn << 6) + (j << 4) + lr) * 64 + kk);
#pragma unroll
        for (int i = 0; i < 2; ++i)
#pragma unroll
          for (int j = 0; j < 4; ++j)
            acc[i][j] = __builtin_amdgcn_mfma_f32_16x16x32_bf16(
                af[i], bfr[j], acc[i][j], 0, 0, 0);
      }
      __syncthreads();
    }
#pragma unroll
    for (int i = 0; i < 2; ++i)
#pragma unroll
      for (int j = 0; j < 4; ++j) {
        int row0 = m0 + (wm << 5) + (i << 4) + (lq << 2);
        int col = n0 + (wn << 6) + (j << 4) + lr;
#pragma unroll
        for (int e = 0; e < 4; ++e)
          gpre[((size_t)(row0 + e) << 11) + col] = acc[i][j][e];
      }
  } else {
    // ---- s GEMM: tile 64x64, BK=64 ----
    const int w2 = wg - 512;
    const int mt = w2 >> 3, nt = w2 & 7;
    const int m0 = mt << 6, n0 = nt << 6;
    f32x4 acc[2][2];
#pragma unroll
    for (int i = 0; i < 2; ++i)
#pragma unroll
      for (int j = 0; j < 2; ++j) acc[i][j] = {0.f, 0.f, 0.f, 0.f};

    for (int k0 = 0; k0 < 512; k0 += 64) {
#pragma unroll
      for (int cc = 0; cc < 4; ++cc) {
        int c = wv * 4 + cc;
        if (c < 8) {
          gl_lds16(hbf + ((size_t)(m0 + (c << 3) + r8) << 9) + (k0 + kk8),
                   (void*)(ldsA + (c << 9)));
        } else {
          int cb = c - 8;
          gl_lds16(Wcs + ((size_t)(n0 + (cb << 3) + r8) << 9) + (k0 + kk8),
                   (void*)(ldsB + (cb << 9)));
        }
      }
      __syncthreads();
#pragma unroll
      for (int kh = 0; kh < 2; ++kh) {
        s16x8 af[2], bfr[2];
        int kk = (kh << 5) + (lq << 3);
#pragma unroll
        for (int i = 0; i < 2; ++i)
          af[i] = *(const s16x8*)(ldsA + ((wm << 5) + (i << 4) + lr) * 64 + kk);
#pragma unroll
        for (int j = 0; j < 2; ++j)
          bfr[j] = *(const s16x8*)(ldsB + ((wn << 5) + (j << 4) + lr) * 64 + kk);
#pragma unroll
        for (int i = 0; i < 2; ++i)
#pragma unroll
          for (int j = 0; j < 2; ++j)
            acc[i][j] = __builtin_amdgcn_mfma_f32_16x16x32_bf16(
                af[i], bfr[j], acc[i][j], 0, 0, 0);
      }
      __syncthreads();
    }
#pragma unroll
    for (int i = 0; i < 2; ++i)
#pragma unroll
      for (int j = 0; j < 2; ++j) {
        int row0 = m0 + (wm << 5) + (i << 4) + (lq << 2);
        int col = n0 + (wn << 5) + (j << 4) + lr;
#pragma unroll
        for (int e = 0; e < 4; ++e)
          sbuf[((size_t)(row0 + e) << 9) + col] = acc[i][j][e];
      }
  }
}

// ------- K_B: attention + LSTM, one batch-row per WG (2048 WGs) ------------
// Gate/const loads issued early (hide HBM latency under the tanh loop).
__global__ __launch_bounds__(256, 4) void darnn_attn_lstm(
    const float* __restrict__ x, const float* __restrict__ W1w,
    const float* __restrict__ W1b, const float* __restrict__ W2b,
    const float* __restrict__ vw, const float* __restrict__ sbuf,
    const float* __restrict__ gpre, const float* __restrict__ Wih,
    const float* __restrict__ bih, const float* __restrict__ bhh,
    float* __restrict__ cst, __hip_bfloat16* __restrict__ hbf,
    float* __restrict__ out, int t)
{
  const int b = blockIdx.x, tid = threadIdx.x;
  const int lane = tid & 63, wv = tid >> 6;

  __shared__ float l_logit[100];
  __shared__ float xs[104];
  __shared__ float l_wm;

  // ---- early loads for the LSTM epilogue (j = tid and tid+256) ----
  const f32x4 g4a = *(const f32x4*)(gpre + ((size_t)b << 11) + (tid << 2));
  const f32x4 g4b = *(const f32x4*)(gpre + ((size_t)b << 11) + (tid << 2) + 1024);
  float wih_[2][4], bia_[2][4], cold[2];
#pragma unroll
  for (int p = 0; p < 2; ++p) {
    int j = tid + (p << 8);
#pragma unroll
    for (int g = 0; g < 4; ++g) {
      wih_[p][g] = Wih[(g << 9) + j];
      bia_[p][g] = bih[(g << 9) + j] + bhh[(g << 9) + j];
    }
    cold[p] = cst[((size_t)b << 9) + j];
  }

  if (tid < 100) xs[tid] = x[b * 100 + tid];

  // per-lane slice of 8 h-indices
  float cw1[8], base[8], vvv[8];
  {
    int h0 = lane * 8;
    const f32x4 s0 = *(const f32x4*)(sbuf + ((size_t)b << 9) + h0);
    const f32x4 s1 = *(const f32x4*)(sbuf + ((size_t)b << 9) + h0 + 4);
#pragma unroll
    for (int e = 0; e < 8; ++e) {
      cw1[e] = W1w[h0 + e];
      vvv[e] = vw[h0 + e];
      float s = (e < 4) ? s0[e] : s1[e - 4];
      base[e] = s + W1b[h0 + e] + W2b[h0 + e];
    }
  }
  __syncthreads();

  // logits over suffix t..99 (wave w: tp = t+w, t+w+4, ...)
  for (int tp = t + wv; tp < 100; tp += 4) {
    float xv = xs[tp];
    float a = 0.f;
#pragma unroll
    for (int e = 0; e < 8; ++e) {
      float arg = fmaf(xv, cw1[e], base[e]);
      a = fmaf(vvv[e], ftanh(arg), a);
    }
    a += __shfl_xor(a, 32); a += __shfl_xor(a, 16); a += __shfl_xor(a, 8);
    a += __shfl_xor(a, 4);  a += __shfl_xor(a, 2);  a += __shfl_xor(a, 1);
    if (lane == 0) l_logit[tp] = a;
  }
  __syncthreads();

  // softmax over [t,100) + weighted mean of x (wave 0)
  if (wv == 0) {
    int t0 = t + lane, t1 = t + 64 + lane;
    float v0 = (t0 < 100) ? l_logit[t0] : -1e30f;
    float v1 = (t1 < 100) ? l_logit[t1] : -1e30f;
    float mx = fmaxf(v0, v1);
    mx = fmaxf(mx, __shfl_xor(mx, 32)); mx = fmaxf(mx, __shfl_xor(mx, 16));
    mx = fmaxf(mx, __shfl_xor(mx, 8));  mx = fmaxf(mx, __shfl_xor(mx, 4));
    mx = fmaxf(mx, __shfl_xor(mx, 2));  mx = fmaxf(mx, __shfl_xor(mx, 1));
    float e0 = (t0 < 100) ? fexp2((v0 - mx) * LOG2E) : 0.f;
    float e1 = (t1 < 100) ? fexp2((v1 - mx) * LOG2E) : 0.f;
    float x0 = (t0 < 100) ? xs[t0] : 0.f;
    float x1 = (t1 < 100) ? xs[t1] : 0.f;
    float se = e0 + e1, sx = e0 * x0 + e1 * x1;
    se += __shfl_xor(se, 32); sx += __shfl_xor(sx, 32);
    se += __shfl_xor(se, 16); sx += __shfl_xor(sx, 16);
    se += __shfl_xor(se, 8);  sx += __shfl_xor(sx, 8);
    se += __shfl_xor(se, 4);  sx += __shfl_xor(sx, 4);
    se += __shfl_xor(se, 2);  sx += __shfl_xor(sx, 2);
    se += __shfl_xor(se, 1);  sx += __shfl_xor(sx, 1);
    if (lane == 0) l_wm = sx * frcp(se * (float)(100 - t));
  }
  __syncthreads();

  // LSTM update for j = tid and tid+256 (gates interleaved: col 4j+g)
  const float wmv = l_wm;
#pragma unroll
  for (int p = 0; p < 2; ++p) {
    int j = tid + (p << 8);
    const f32x4 g4 = (p == 0) ? g4a : g4b;
    float gi = fmaf(wmv, wih_[p][0], bia_[p][0]) + g4[0];
    float gf = fmaf(wmv, wih_[p][1], bia_[p][1]) + g4[1];
    float gg = fmaf(wmv, wih_[p][2], bia_[p][2]) + g4[2];
    float go = fmaf(wmv, wih_[p][3], bia_[p][3]) + g4[3];
    float cn = fsig(gf) * cold[p] + fsig(gi) * ftanh(gg);
    float hn = fsig(go) * ftanh(cn);
    size_t cidx = ((size_t)b << 9) + j;
    cst[cidx] = cn;
    hbf[cidx] = __float2bfloat16(hn);
    if (t >= 84) out[((size_t)b << 13) + ((size_t)(t - 84) << 9) + j] = hn;
  }
}

extern "C" void kernel_launch(void* const* d_in, const int* in_sizes, int n_in,
                              void* d_out, int out_size, void* d_ws, size_t ws_size,
                              hipStream_t stream) {
  const float* x   = (const float*)d_in[0];
  const float* W1w = (const float*)d_in[1];
  const float* W1b = (const float*)d_in[2];
  const float* W2w = (const float*)d_in[3];
  const float* W2b = (const float*)d_in[4];
  const float* vw  = (const float*)d_in[5];
  // d_in[6] = v_b : cancels in softmax, unused
  const float* Wih = (const float*)d_in[7];
  const float* bih = (const float*)d_in[8];
  const float* Whh = (const float*)d_in[9];
  const float* bhh = (const float*)d_in[10];
  float* out = (float*)d_out;

  char* ws = (char*)d_ws;
  __hip_bfloat16* Wcs = (__hip_bfloat16*)(ws);
  __hip_bfloat16* Wcg = (__hip_bfloat16*)(ws + 524288);
  __hip_bfloat16* hbf = (__hip_bfloat16*)(ws + 2621440);
  float* cst  = (float*)(ws + 4718592);
  float* sbuf = (float*)(ws + 8912896);
  float* gpre = (float*)(ws + 13107200);

  darnn_prologue<<<dim3(512), dim3(256), 0, stream>>>(
      W2w, Whh, Wcs, Wcg, hbf, cst);
  for (int t = 0; t < 100; ++t) {
    darnn_gemms<<<dim3(768), dim3(256), 0, stream>>>(hbf, Wcs, Wcg, sbuf, gpre);
    darnn_attn_lstm<<<dim3(2048), dim3(256), 0, stream>>>(
        x, W1w, W1b, W2b, vw, sbuf, gpre, Wih, bih, bhh, cst, hbf, out, t);
  }
}